// Round 5
// baseline (307.208 us; speedup 1.0000x reference)
//
#include <hip/hip_runtime.h>

#define BATCH 8
#define HH 2048
#define WW 2048
#define R 8
#define TAPS (2 * R + 1)   // 17
#define SW 64              // strip width (output cols per block)
#define SEG 128            // output rows per block
#define NIT (SEG / 16)     // 8 iterations of 16 rows
#define RINGN 64           // ring slots (power of 2 -> &63 addressing)
#define PIT 68             // ring row pitch (floats): 68*4=272 B, 16B-aligned, mod-32==4 bank stagger

// Fused separable circular Gaussian blur (== irfft2(rfft2(x)*rfft2(fftshift(g)))
// for sigma=2; tail beyond |d|=8 is ~1.7e-5 relative).
//
// v8: software-pipelined rolling strip (v7's minimal 34 FMA/output, fixed latency).
//   v7 post-mortem: busy fell 56->46 us but elapsed rose to 124: every phase
//   started cold because __syncthreads' implicit vmcnt(0) drained the loads and
//   VGPR=32 scheduling serialized load->use. v8 keeps loads IN FLIGHT across
//   barriers (guide T3/T4 pattern):
//     per iter: HCONV (consume prefetched regs -> ds_write slots [16i+32,16i+48))
//               -> issue next 5 float4 loads (uncommitted)
//               -> CONVV (ds_read slots [16i,16i+32) -> FMA -> global store)
//               -> s_waitcnt lgkmcnt(0); sched_barrier; raw s_barrier (NO vmcnt drain)
//   Ring hazard proof: write-set [16i+32,16i+48) and read-set [16i,16i+32) are
//   disjoint every iteration (RINGN=64 >= 48 live slots); per-wave lgkmcnt(0)
//   before each barrier makes all LDS writes visible; slot m is rewritten (as
//   m+64) two iterations after its last read, with barriers between.
//   Full unroll -> all slot indices & wrap branches compile-time; no divergent
//   guards, no launch_bounds min-wave cap (v6 spill lesson).
// Bank analysis: HCONV ds_write_b128: 16 lanes cover 256 contiguous bytes per
// row -> all 32 banks, conflict-free. CONVV ds_read_b32: lane==column,
// 2 lanes/bank = free. Global loads: 4x256B segments per instr; stores: 256B
// contiguous per row. float4 groups 4-aligned -> never straddle the wrap.
__global__ __launch_bounds__(256)
void gauss_blur_v8(const float* __restrict__ x,
                   const float* __restrict__ sigma_p,
                   float* __restrict__ out) {
    __shared__ float ring[RINGN * PIT];   // 64*68*4 = 17408 B

    const int tid = threadIdx.x;
    const int x0 = blockIdx.x * SW;
    const int y0 = blockIdx.y * SEG;
    const float* __restrict__ xb = x   + ((long)blockIdx.z << 22);  // 2048*2048/image
    float* __restrict__       ob = out + ((long)blockIdx.z << 22);

    // 1D Gaussian taps from the runtime sigma scalar (relu + 1e-6 per ref).
    float w[TAPS];
    float wsum = 0.0f;
    {
        float sg = fmaxf(sigma_p[0], 0.0f) + 1e-6f;
        float c = -1.0f / (2.0f * sg * sg);
        #pragma unroll
        for (int k = 0; k < TAPS; ++k) {
            float d = (float)(k - R);
            w[k] = __expf(d * d * c);
            wsum += w[k];
        }
    }
    const float inv = 1.0f / wsum;   // 1D norm; applied once per pass (2D = inv^2)

    // H mapping: 16 rows x 16 col-groups of 4 outputs. Masked so ranges are provable.
    const int h_r = (tid >> 4) & 15;      // row within 16-row batch
    const int h_c = (tid & 15) * 4;       // first output col of the group
    // V mapping: 4 row-groups x 64 columns, 4 outputs/thread.
    const int v_x = tid & 63;
    const int v_r = ((tid >> 6) & 3) * 4;

    const bool interior = (x0 >= R) && (x0 + SW + R <= WW);
    const int c0 = x0 + h_c - R;          // window start col (may be <0 / >=WW on border strips)

    float4 p0, p1, p2, p3, p4;            // prefetch registers (20-float window)

    // Issue the 5 global loads for the input row of ring slot (s + h_r).
    auto LOADH = [&](int s) {
        int gy = (y0 + s + h_r - R) & (HH - 1);
        const float* rp = xb + ((long)gy << 11);
        if (interior) {
            const float4* q = (const float4*)(rp + c0);
            p0 = q[0]; p1 = q[1]; p2 = q[2]; p3 = q[3]; p4 = q[4];
        } else {
            p0 = *(const float4*)(rp + ((c0 +  0) & (WW - 1)));
            p1 = *(const float4*)(rp + ((c0 +  4) & (WW - 1)));
            p2 = *(const float4*)(rp + ((c0 +  8) & (WW - 1)));
            p3 = *(const float4*)(rp + ((c0 + 12) & (WW - 1)));
            p4 = *(const float4*)(rp + ((c0 + 16) & (WW - 1)));
        }
    };

    // Consume prefetch regs: horizontal conv -> ring slot (s + h_r), 4 mid values.
    auto HCONV = [&](int s) {
        float v[20];
        v[ 0]=p0.x; v[ 1]=p0.y; v[ 2]=p0.z; v[ 3]=p0.w;
        v[ 4]=p1.x; v[ 5]=p1.y; v[ 6]=p1.z; v[ 7]=p1.w;
        v[ 8]=p2.x; v[ 9]=p2.y; v[10]=p2.z; v[11]=p2.w;
        v[12]=p3.x; v[13]=p3.y; v[14]=p3.z; v[15]=p3.w;
        v[16]=p4.x; v[17]=p4.y; v[18]=p4.z; v[19]=p4.w;
        float4 m4;
        float* mp = (float*)&m4;
        #pragma unroll
        for (int jj = 0; jj < 4; ++jj) {
            float acc = 0.0f;
            #pragma unroll
            for (int k = 0; k < TAPS; ++k) acc += w[k] * v[jj + k];
            mp[jj] = acc * inv;
        }
        int slot = (s + h_r) & (RINGN - 1);
        *(float4*)&ring[slot * PIT + h_c] = m4;
    };

    // Vertical conv for output rows [16i+v_r, 16i+v_r+4) at column v_x.
    // Reads ring slots 16i+v_r .. +19 (slot m = mid of image row y0+m-8).
    auto CONVV = [&](int i) {
        const int r0t = ((i << 4) + v_r) & (RINGN - 1);
        float u[20];
        if (r0t <= RINGN - 20) {          // compile-time after unroll (v_r <= 12 provable)
            const float* b = &ring[r0t * PIT + v_x];
            #pragma unroll
            for (int j = 0; j < 20; ++j) u[j] = b[j * PIT];   // imm-offset ds_read_b32
        } else {
            #pragma unroll
            for (int j = 0; j < 20; ++j)
                u[j] = ring[((r0t + j) & (RINGN - 1)) * PIT + v_x];
        }
        float* op = ob + ((long)(y0 + (i << 4) + v_r) << 11) + x0 + v_x;
        #pragma unroll
        for (int jj = 0; jj < 4; ++jj) {
            float acc = 0.0f;
            #pragma unroll
            for (int k = 0; k < TAPS; ++k) acc += w[k] * u[jj + k];
            op[(long)jj << 11] = acc * inv;
        }
    };

    // Prologue: prime ring slots [0,32); leave rows for [32,48) in flight.
    LOADH(0);  HCONV(0);
    LOADH(16); HCONV(16);
    LOADH(32);
    asm volatile("s_waitcnt lgkmcnt(0)" ::: "memory");
    __builtin_amdgcn_sched_barrier(0);
    __builtin_amdgcn_s_barrier();
    __builtin_amdgcn_sched_barrier(0);

    #pragma unroll
    for (int i = 0; i < NIT; ++i) {
        if (i < NIT - 1) HCONV((i << 4) + 32);   // write [16i+32,16i+48) (disjoint from reads)
        if (i < NIT - 2) LOADH((i << 4) + 48);   // issue next prefetch; stays in flight
        CONVV(i);                                 // read [16i,16i+32), store 16 output rows
        if (i < NIT - 1) {
            asm volatile("s_waitcnt lgkmcnt(0)" ::: "memory");   // LDS ops visible; vmcnt NOT drained
            __builtin_amdgcn_sched_barrier(0);
            __builtin_amdgcn_s_barrier();
            __builtin_amdgcn_sched_barrier(0);
        }
    }
}

extern "C" void kernel_launch(void* const* d_in, const int* in_sizes, int n_in,
                              void* d_out, int out_size, void* d_ws, size_t ws_size,
                              hipStream_t stream) {
    const float* x      = (const float*)d_in[0];
    const float* sigma_ = (const float*)d_in[1];
    float* out          = (float*)d_out;

    dim3 grid(WW / SW, HH / SEG, BATCH);   // 32 x 16 x 8 = 4096 blocks
    gauss_blur_v8<<<grid, 256, 0, stream>>>(x, sigma_, out);
}

// Round 6
// 231.523 us; speedup vs baseline: 1.3269x; 1.3269x over previous
//
#include <hip/hip_runtime.h>

#define BATCH 8
#define HH 2048
#define WW 2048
#define R 8
#define TAPS (2 * R + 1)   // 17
#define TX 64              // tile width  (outputs)
#define TY 48              // tile height (outputs)
#define SHW (TX + 2 * R)   // 80 staged floats per row
#define SHH (TY + 2 * R)   // 64 staged rows
#define PIT 84             // pitch: 84 mod 32 = 20 -> 8-lane b128 phases cover all 32 banks (v3-verified)
#define GY 43              // ceil(2048/48); last row of blocks wraps circularly (duplicate-value writes)

// Fused separable circular Gaussian blur (== irfft2(rfft2(x)*rfft2(fftshift(g)))
// for sigma=2; tail beyond |d|=8 is ~1.7e-5 relative).
//
// v9: v5's exact bulk-phase structure, redundancy cut 2.0x -> 1.33x.
//   Evidence: v5 (bulk phases, big MLP) = 97 us; v7/v8 (fine-grained phases /
//   hand pipelining) = 124/152 us. v6 (tile change) failed only via spill
//   (launch-bounds cap + divergent guard). So: keep v5 mechanics untouched,
//   change only the tile to 64x48:
//     - staged 64x80 @ pitch 84 = 21504 B -> still 7 blocks/CU.
//     - horizontal tasks = 64 rows x 4 groups = EXACTLY 256: one uniform
//       in-place batch, no divergence, no min-wave cap.
//     - stage-1 = 1280 float4 groups = exactly 5/thread, uniform.
//     - FMA/output 51 -> 39.7; staged floats/output 2.25 -> 1.67.
//   48 does not divide 2048: grid.y=43, block y=42 computes rows 2016..2063
//   which wrap to 2016..2047 + 0..15; circular conv is 2048-periodic so the
//   wrapped writes duplicate block y=0's values exactly (benign).
// Bank analysis (all v3/v5-verified patterns): stage-1 writes consecutive-lane
// consecutive-address; horizontal b128 row-stride 84 (mod 32 == 20: each 8-lane
// phase covers all 32 banks); vertical b32 lane==column (2 lanes/bank = free,
// m136). Global accesses coalesced (256B/wave-instr min); float4 groups are
// 4-aligned so the circular wrap never straddles a group.
__global__ __launch_bounds__(256)
void gauss_blur_v9(const float* __restrict__ x,
                   const float* __restrict__ sigma_p,
                   float* __restrict__ out) {
    __shared__ float s[SHH * PIT];   // 64*84*4 = 21504 B

    const int tid = threadIdx.x;
    const int tx0 = blockIdx.x * TX;
    const int ty0 = blockIdx.y * TY;
    const float* __restrict__ xb = x   + ((long)blockIdx.z << 22);  // 2048*2048 per image
    float* __restrict__       ob = out + ((long)blockIdx.z << 22);

    // 1D Gaussian taps from the runtime sigma scalar (relu + 1e-6 per ref).
    float w[TAPS];
    float wsum = 0.0f;
    {
        float sg = fmaxf(sigma_p[0], 0.0f) + 1e-6f;
        float c = -1.0f / (2.0f * sg * sg);
        #pragma unroll
        for (int k = 0; k < TAPS; ++k) {
            float d = (float)(k - R);
            w[k] = __expf(d * d * c);
            wsum += w[k];
        }
    }
    const float inv = 1.0f / wsum;   // 1D norm; applied once per pass (2D = inv^2)

    // Stage 1: load 64x80 halo tile as float4 groups, coalesced. 1280 groups,
    // exactly 5 per thread.
    #pragma unroll
    for (int it = 0; it < 5; ++it) {
        int i = tid + 256 * it;
        int r = i / 20;                       // const-div -> mul_hi
        int g = i - r * 20;
        int gy = (ty0 + r - R) & (HH - 1);
        int gx = (tx0 + 4 * g - R) & (WW - 1);
        *(float4*)&s[r * PIT + 4 * g] = *(const float4*)&xb[((long)gy << 11) + gx];
    }
    __syncthreads();

    // Stage 2: horizontal pass, in place. Exactly 256 tasks: (row, col-group).
    // s[r][c] holds x[gy(r)][tx0 + c - 8]; mid[r][m] = sum_k w[k]*s[r][m+k],
    // stored back at s[r][m].
    const int hr = tid & 63;          // row 0..63
    const int hc = (tid >> 6) * 16;   // first output col of the group (0/16/32/48)
    float v[32];
    {
        const float4* src = (const float4*)&s[hr * PIT + hc];
        #pragma unroll
        for (int j = 0; j < 8; ++j) {
            float4 q = src[j];
            v[4*j+0] = q.x; v[4*j+1] = q.y; v[4*j+2] = q.z; v[4*j+3] = q.w;
        }
    }
    __syncthreads();   // ALL window reads complete before any in-place overwrite
    {
        float4* dst = (float4*)&s[hr * PIT + hc];
        #pragma unroll
        for (int q4 = 0; q4 < 4; ++q4) {
            float4 m4;
            float* mp = (float*)&m4;
            #pragma unroll
            for (int jj = 0; jj < 4; ++jj) {
                float acc = 0.0f;
                #pragma unroll
                for (int k = 0; k < TAPS; ++k) acc += w[k] * v[q4*4 + jj + k];
                mp[jj] = acc * inv;
            }
            dst[q4] = m4;
        }
    }
    __syncthreads();

    // Stage 3: vertical pass. 3072 outputs = 4 y-groups x 64 cols x 12 rows each.
    // s row r now holds mid of image row (ty0 + r - 8): output row ty0+t needs
    // s rows t..t+16.
    {
        int xx = tid & 63;
        int t0 = (tid >> 6) * 12;     // first output row (0/12/24/36)
        float u[28];
        const float* b = &s[t0 * PIT + xx];
        #pragma unroll
        for (int j = 0; j < 28; ++j) u[j] = b[j * PIT];   // imm-offset ds_read_b32
        #pragma unroll
        for (int jj = 0; jj < 12; ++jj) {
            float acc = 0.0f;
            #pragma unroll
            for (int k = 0; k < TAPS; ++k) acc += w[k] * u[jj + k];
            int orow = (ty0 + t0 + jj) & (HH - 1);        // wrap for the tail block row
            ob[((long)orow << 11) + (tx0 + xx)] = acc * inv;
        }
    }
}

extern "C" void kernel_launch(void* const* d_in, const int* in_sizes, int n_in,
                              void* d_out, int out_size, void* d_ws, size_t ws_size,
                              hipStream_t stream) {
    const float* x      = (const float*)d_in[0];
    const float* sigma_ = (const float*)d_in[1];
    float* out          = (float*)d_out;

    dim3 grid(WW / TX, GY, BATCH);   // 32 x 43 x 8 = 11008 blocks
    gauss_blur_v9<<<grid, 256, 0, stream>>>(x, sigma_, out);
}

// Round 7
// 231.289 us; speedup vs baseline: 1.3282x; 1.0010x over previous
//
#include <hip/hip_runtime.h>

#define BATCH 8
#define HH 2048
#define WW 2048
#define R 8
#define TAPS (2 * R + 1)   // 17
#define TX 64              // tile width  (outputs)
#define TY 48              // tile height (outputs)
#define SHW (TX + 2 * R)   // 80 staged floats per row (+4 pad -> PIT)
#define SHH (TY + 2 * R)   // 64 staged rows
#define PIT 84             // pitch: 84 mod 32 = 20 (v3-verified conflict-free); 336 B = 21 x 16 B
#define GY 43              // ceil(2048/48); tail block row wraps circularly (duplicate-value writes)
#define NB (SHH * 21)      // 1344 staged 16-byte blocks (incl. 1 pad block per row)

// Fused separable circular Gaussian blur (== irfft2(rfft2(x)*rfft2(fftshift(g)))
// for sigma=2; tail beyond |d|=8 is ~1.7e-5 relative).
//
// v10: v9 + async global->LDS staging + normalized weights.
//   v9 (64x48 tile, 1.33x redundancy, bulk phases) ~77 us. Stage-1 was still
//   load->VGPR->wait->ds_write. Replaced with __builtin_amdgcn_global_load_lds
//   width=16: HW writes LDS at (wave-uniform base + lane*16), so the GLOBAL
//   source is pre-swizzled instead of the LDS dest (guide m173):
//     16B block b -> row r=b/21, col4=b%21  (row byte-pitch 336 = 21*16, so a
//     16B block never straddles a row). Linear LDS block b == float offset
//     84*r + 4*c4 -- byte-identical to v9's layout. c4==20 is the 4-float pad:
//     never read (horizontal windows end at col 79), loaded with a harmless
//     in-range address so no special-casing or masking is needed.
//   1344 blocks = 5 full 256-thread issues + 1 wave-uniform partial (wave 0).
//   __syncthreads() drains vmcnt(0) -> all async LDS writes visible.
//   Also: inv folded into wn[k] once (saves ~2.3 VALU mul/output).
// Bank analysis unchanged from v9 (all verified patterns): horizontal b128
// row-stride 84 (mod 32 == 20: 8-lane phases cover all 32 banks); vertical b32
// lane==column (2 lanes/bank = free). Global: 336B contiguous runs per row
// (coalesced); 16B groups 16B-aligned, never straddle the circular wrap.
__global__ __launch_bounds__(256)
void gauss_blur_v10(const float* __restrict__ x,
                    const float* __restrict__ sigma_p,
                    float* __restrict__ out) {
    __shared__ float s[SHH * PIT];   // 64*84*4 = 21504 B -> 7 blocks/CU

    const int tid = threadIdx.x;
    const int tx0 = blockIdx.x * TX;
    const int ty0 = blockIdx.y * TY;
    const float* __restrict__ xb = x   + ((long)blockIdx.z << 22);  // 2048*2048 per image
    float* __restrict__       ob = out + ((long)blockIdx.z << 22);

    // 1D Gaussian taps (relu(sigma)+1e-6 per ref), pre-normalized: wn = w/sum(w).
    float wn[TAPS];
    {
        float w[TAPS];
        float wsum = 0.0f;
        float sg = fmaxf(sigma_p[0], 0.0f) + 1e-6f;
        float c = -1.0f / (2.0f * sg * sg);
        #pragma unroll
        for (int k = 0; k < TAPS; ++k) {
            float d = (float)(k - R);
            w[k] = __expf(d * d * c);
            wsum += w[k];
        }
        float inv = 1.0f / wsum;
        #pragma unroll
        for (int k = 0; k < TAPS; ++k) wn[k] = w[k] * inv;
    }

    // Stage 1: 64x80(+pad) halo tile, async global->LDS.
#if defined(__has_builtin) && __has_builtin(__builtin_amdgcn_global_load_lds)
    {
        const int wave = tid >> 6;
        const int lane = tid & 63;
        #pragma unroll
        for (int it = 0; it < 6; ++it) {
            const int b0 = it * 256 + wave * 64;      // wave-uniform LDS base block
            if (b0 < NB) {                            // wave-uniform branch (it==5 -> wave 0 only)
                int b  = b0 + lane;
                int r  = b / 21;                      // const-div -> mul_hi
                int c4 = b - r * 21;
                int gy = (ty0 + r - R) & (HH - 1);
                int gx = (tx0 + 4 * c4 - R) & (WW - 1);   // c4==20 -> pad: valid addr, never read
                __builtin_amdgcn_global_load_lds(
                    (const __attribute__((address_space(1))) void*)&xb[((long)gy << 11) + gx],
                    (__attribute__((address_space(3))) void*)&s[4 * b],
                    16, 0, 0);
            }
        }
    }
#else
    #pragma unroll
    for (int it = 0; it < 5; ++it) {   // v9 manual staging fallback (20 data groups/row)
        int i = tid + 256 * it;
        int r = i / 20;
        int g = i - r * 20;
        int gy = (ty0 + r - R) & (HH - 1);
        int gx = (tx0 + 4 * g - R) & (WW - 1);
        *(float4*)&s[r * PIT + 4 * g] = *(const float4*)&xb[((long)gy << 11) + gx];
    }
#endif
    __syncthreads();   // drains vmcnt(0): all staged data visible in LDS

    // Stage 2: horizontal pass, in place. Exactly 256 tasks: (row, col-group).
    // s[r][c] holds x[gy(r)][tx0 + c - 8]; mid[r][m] = sum_k wn[k]*s[r][m+k].
    const int hr = tid & 63;          // row 0..63
    const int hc = (tid >> 6) * 16;   // first output col of the group (0/16/32/48)
    float v[32];
    {
        const float4* src = (const float4*)&s[hr * PIT + hc];
        #pragma unroll
        for (int j = 0; j < 8; ++j) {
            float4 q = src[j];
            v[4*j+0] = q.x; v[4*j+1] = q.y; v[4*j+2] = q.z; v[4*j+3] = q.w;
        }
    }
    __syncthreads();   // ALL window reads complete before any in-place overwrite
    {
        float4* dst = (float4*)&s[hr * PIT + hc];
        #pragma unroll
        for (int q4 = 0; q4 < 4; ++q4) {
            float4 m4;
            float* mp = (float*)&m4;
            #pragma unroll
            for (int jj = 0; jj < 4; ++jj) {
                float acc = 0.0f;
                #pragma unroll
                for (int k = 0; k < TAPS; ++k) acc += wn[k] * v[q4*4 + jj + k];
                mp[jj] = acc;
            }
            dst[q4] = m4;
        }
    }
    __syncthreads();

    // Stage 3: vertical pass. 3072 outputs = 4 y-groups x 64 cols x 12 rows each.
    // s row r holds mid of image row (ty0 + r - 8): output row ty0+t needs rows t..t+16.
    {
        int xx = tid & 63;
        int t0 = (tid >> 6) * 12;     // first output row of the group (0/12/24/36)
        float u[28];
        const float* b = &s[t0 * PIT + xx];
        #pragma unroll
        for (int j = 0; j < 28; ++j) u[j] = b[j * PIT];   // imm-offset ds_read_b32
        #pragma unroll
        for (int jj = 0; jj < 12; ++jj) {
            float acc = 0.0f;
            #pragma unroll
            for (int k = 0; k < TAPS; ++k) acc += wn[k] * u[jj + k];
            int orow = (ty0 + t0 + jj) & (HH - 1);        // wrap for the tail block row
            ob[((long)orow << 11) + (tx0 + xx)] = acc;
        }
    }
}

extern "C" void kernel_launch(void* const* d_in, const int* in_sizes, int n_in,
                              void* d_out, int out_size, void* d_ws, size_t ws_size,
                              hipStream_t stream) {
    const float* x      = (const float*)d_in[0];
    const float* sigma_ = (const float*)d_in[1];
    float* out          = (float*)d_out;

    dim3 grid(WW / TX, GY, BATCH);   // 32 x 43 x 8 = 11008 blocks
    gauss_blur_v10<<<grid, 256, 0, stream>>>(x, sigma_, out);
}